// Round 5
// baseline (6474.986 us; speedup 1.0000x reference)
//
#include <hip/hip_runtime.h>
#include <hip/hip_bf16.h>

// ---------------- sizes ----------------
#define T_STEPS 256
#define MDIM 1024      // MEM_DIM == IN_DIM
#define MROWS 512      // attention memory rows
#define NBLK 256       // persistent grid
#define NTHR 512

// ws float offsets
#define OFF_WG      0u                     // [1024][4096] interleaved (i,o,u,f) per gate
#define OFF_WATT    4194304u               // [1024][1024] transposed W_attnh top
#define OFF_HPRE    5242880u               // [512][1024]
#define OFF_XIOU    5767168u               // [256][3072]
#define OFF_XF      6553600u               // [256][1024]
#define OFF_HCOL    6815744u               // [1024]
#define OFF_H       6816768u               // [1024]
#define OFF_C       (OFF_H + 1024u)        // [1024]
#define OFF_BAR     (OFF_H + 2048u)        // 4096 u32: 256 slots, stride 16 (64B lines)
#define OFF_HNEW    (OFF_H + 6144u)        // [1024]
#define OFF_ATTV    (OFF_H + 7168u)        // [1024]
#define OFF_E       (OFF_H + 8192u)        // [512]

__device__ inline float fast_tanh(float v) {
    float x = fminf(fmaxf(v, -15.f), 15.f);
    float z = __expf(2.f * x);
    return (z - 1.f) / (z + 1.f);
}
__device__ inline float sigm(float v) { return 1.f / (1.f + __expf(-v)); }

__device__ inline float wave_red(float v) {
#pragma unroll
    for (int s = 32; s > 0; s >>= 1) v += __shfl_down(v, s, 64);
    return v;
}

// device-scope relaxed atomics: bypass L2 (serialize at LLC), emit NO buffer_inv
__device__ inline float gload(const float* p) {
    return __hip_atomic_load(p, __ATOMIC_RELAXED, __HIP_MEMORY_SCOPE_AGENT);
}
__device__ inline void gstore(float* p, float v) {
    __hip_atomic_store(p, v, __ATOMIC_RELAXED, __HIP_MEMORY_SCOPE_AGENT);
}

// Flat slot-array barrier, parallel detection, NO acquire fence (keeps L2 warm).
// Block b release-stores epoch to its own 64B-padded slot (no RMW anywhere);
// threads 0..255 poll one slot each. Correctness: __syncthreads drains vmcnt
// (agent-scope data stores LLC-acked) before the release slot store; slot
// visibility => that block's data is at LLC; post-barrier reads are LLC-direct.
__device__ inline void gsync(unsigned* bar, unsigned ep) {
    __syncthreads();
    if (threadIdx.x == 0)
        __hip_atomic_store(&bar[blockIdx.x * 16], ep + 1u, __ATOMIC_RELEASE,
                           __HIP_MEMORY_SCOPE_AGENT);
    if (threadIdx.x < NBLK) {
        while (__hip_atomic_load(&bar[threadIdx.x * 16], __ATOMIC_RELAXED,
                                 __HIP_MEMORY_SCOPE_AGENT) < ep + 1u)
            __builtin_amdgcn_s_sleep(1);
    }
    __asm__ volatile("" ::: "memory");
    __syncthreads();
}

// -------- precompute kernels --------

// Wg[k][4g+{0,1,2,3}] = {W_iouh[k][g], W_iouh[k][m+g], W_iouh[k][2m+g], W_fh[k][g]}
__global__ void build_wg(const float* __restrict__ Wiouh, const float* __restrict__ Wfh,
                         float* __restrict__ Wg) {
    int k = blockIdx.y;
    int g = blockIdx.x * 256 + threadIdx.x;
    float4 v;
    v.x = Wiouh[k * 3072 + g];
    v.y = Wiouh[k * 3072 + 1024 + g];
    v.z = Wiouh[k * 3072 + 2048 + g];
    v.w = Wfh[k * 1024 + g];
    *(float4*)(Wg + (size_t)k * 4096 + 4 * g) = v;
}

// WatT[j][k] = W_attnh[k][j] for k<1024 (top half)
__global__ void transpose_k(const float* __restrict__ src, float* __restrict__ dst) {
    __shared__ float tile[32][33];
    int jx = blockIdx.x * 32 + threadIdx.x;
    int k0 = blockIdx.y * 32;
    for (int i = threadIdx.y; i < 32; i += 8)
        tile[i][threadIdx.x] = src[(size_t)(k0 + i) * 1024 + jx];
    __syncthreads();
    int kx = k0 + threadIdx.x;
    int j0 = blockIdx.x * 32;
    for (int i = threadIdx.y; i < 32; i += 8)
        dst[(size_t)(j0 + i) * 1024 + kx] = tile[threadIdx.x][i];
}

// C[M,N] = A[M,K] @ B[K,N] + b1 + b2 ; M,N multiples of 64, K multiple of 16
__global__ __launch_bounds__(256) void gemm_bias(const float* __restrict__ A,
                                                 const float* __restrict__ B,
                                                 const float* __restrict__ b1,
                                                 const float* __restrict__ b2,
                                                 float* __restrict__ C,
                                                 int M, int N, int K) {
    __shared__ float As[16][68];
    __shared__ float Bs[16][68];
    int t = threadIdx.x;
    int m0 = blockIdx.y * 64, n0 = blockIdx.x * 64;
    int tx = t & 15, ty = t >> 4;
    float acc[4][4] = {};
    for (int kk = 0; kk < K; kk += 16) {
        {
            int m = t >> 2, k4 = (t & 3) * 4;
            const float4 a4 = *(const float4*)(A + (size_t)(m0 + m) * K + kk + k4);
            As[k4 + 0][m] = a4.x; As[k4 + 1][m] = a4.y;
            As[k4 + 2][m] = a4.z; As[k4 + 3][m] = a4.w;
            int kb = t >> 4, n = (t & 15) * 4;
            const float4 b4 = *(const float4*)(B + (size_t)(kk + kb) * N + n0 + n);
            *(float4*)&Bs[kb][n] = b4;
        }
        __syncthreads();
#pragma unroll
        for (int k = 0; k < 16; k++) {
            float a[4], b[4];
            *(float4*)a = *(const float4*)&As[k][ty * 4];
            *(float4*)b = *(const float4*)&Bs[k][tx * 4];
#pragma unroll
            for (int i = 0; i < 4; i++)
#pragma unroll
                for (int j = 0; j < 4; j++)
                    acc[i][j] = fmaf(a[i], b[j], acc[i][j]);
        }
        __syncthreads();
    }
#pragma unroll
    for (int i = 0; i < 4; i++) {
        int m = m0 + ty * 4 + i;
#pragma unroll
        for (int j = 0; j < 4; j++) {
            int n = n0 + tx * 4 + j;
            float v = acc[i][j];
            if (b1) v += b1[n];
            if (b2) v += b2[n];
            C[(size_t)m * N + n] = v;
        }
    }
}

__global__ void colsum_k(const float* __restrict__ H, float* __restrict__ out) {
    int k = blockIdx.x * 256 + threadIdx.x;
    float s = 0.f;
#pragma unroll 8
    for (int r = 0; r < MROWS; r++) s += H[(size_t)r * MDIM + k];
    out[k] = s;
}

// -------- persistent recurrent kernel --------
__global__ __launch_bounds__(NTHR) void recurrent(
    const float* __restrict__ Wg, const float* __restrict__ WatT,
    const float* __restrict__ Hpre, const float* __restrict__ H,
    const float* __restrict__ Hcol, const float* __restrict__ X_iou,
    const float* __restrict__ X_f, const float* __restrict__ Wa,
    float* h, float* c, float* h_new, float* att_v, float* e,
    unsigned* bar, float* out) {

    const int b = blockIdx.x, t = threadIdx.x;
    const int x = b & 7, y = b >> 3;   // XCD-contiguous slices
    unsigned ep = 0;
    __shared__ float smem[1664];

    for (int st = 0; st < T_STEPS; st++) {
        // ---- Phase A: gates + h_new (4 gate columns per block) ----
        {
            float* hs = smem;            // padded h copy, idx k+(k>>5), 1056
            float* red = smem + 1056;    // [32][16]
            float* dotb = smem + 1568;   // [16]
            float h0 = gload(h + t), h1 = gload(h + t + 512);
            hs[t + (t >> 5)] = h0;
            { int k2 = t + 512; hs[k2 + (k2 >> 5)] = h1; }
            __syncthreads();
            const int jt = t & 15, kq = t >> 4;   // jt: column, kq: k-slice of 32
            const int j0 = x * 512 + y * 16;
            const float* wp = Wg + (size_t)(kq * 32) * 4096 + j0 + jt;
            float acc = 0.f;
#pragma unroll 8
            for (int i = 0; i < 32; i++) {
                int k = kq * 32 + i;
                acc = fmaf(hs[k + (k >> 5)], wp[(size_t)i * 4096], acc);
            }
            red[kq * 16 + jt] = acc;
            __syncthreads();
            if (t < 16) {
                float s = 0.f;
#pragma unroll
                for (int q = 0; q < 32; q++) s += red[q * 16 + t];
                dotb[t] = s;
            }
            __syncthreads();
            if (t < 4) {
                int g = x * 128 + y * 4 + t;
                float di = dotb[t * 4 + 0] + X_iou[(size_t)st * 3072 + g];
                float doo = dotb[t * 4 + 1] + X_iou[(size_t)st * 3072 + 1024 + g];
                float du = dotb[t * 4 + 2] + X_iou[(size_t)st * 3072 + 2048 + g];
                float df = dotb[t * 4 + 3] + X_f[(size_t)st * 1024 + g];
                float ig = sigm(di), og = sigm(doo), fg = sigm(df);
                float ug = fast_tanh(du);
                float cn = ig * ug + fg * c[g];
                c[g] = cn;
                gstore(h_new + g, og * fast_tanh(cn));
            }
        }
        gsync(bar, ep++);

        // ---- Phase B: att_v = h_new @ W_attnh_top (4 rows per block) ----
        {
            float* hn = smem;            // [1024] staged h_new
            hn[t] = gload(h_new + t);
            hn[t + 512] = gload(h_new + t + 512);
            __syncthreads();
            const int tr = t >> 7, li = t & 127;
            int j = x * 128 + y * 4 + tr;
            const float* wr = WatT + (size_t)j * 1024;
            float4 w0 = *(const float4*)(wr + li * 4);
            float4 w1 = *(const float4*)(wr + 512 + li * 4);
            float4 a0 = *(const float4*)&hn[li * 4];
            float4 a1 = *(const float4*)&hn[512 + li * 4];
            float acc = w0.x * a0.x + w0.y * a0.y + w0.z * a0.z + w0.w * a0.w
                      + w1.x * a1.x + w1.y * a1.y + w1.z * a1.z + w1.w * a1.w;
            acc = wave_red(acc);
            __syncthreads();     // smem reuse guard (hn -> reduction slots)
            if ((t & 63) == 0) smem[1024 + (t >> 6)] = acc;
            __syncthreads();
            if (t < 4) gstore(att_v + x * 128 + y * 4 + t,
                              smem[1024 + t * 2] + smem[1024 + t * 2 + 1]);
        }
        gsync(bar, ep++);

        // ---- Phase C: scores -> e (2 rows per block) ----
        {
            float* av = smem;            // [1024] staged att_v
            av[t] = gload(att_v + t);
            av[t + 512] = gload(att_v + t + 512);
            __syncthreads();
            const int rr = t >> 8, li = t & 255;
            int r = x * 64 + y * 2 + rr;
            int k4 = li * 4;
            float4 hp = *(const float4*)(Hpre + (size_t)r * 1024 + k4);
            float4 a4 = *(const float4*)&av[k4];
            float4 wa = *(const float4*)(Wa + k4);
            float acc = fast_tanh(hp.x + a4.x) * wa.x + fast_tanh(hp.y + a4.y) * wa.y
                      + fast_tanh(hp.z + a4.z) * wa.z + fast_tanh(hp.w + a4.w) * wa.w;
            acc = wave_red(acc);
            __syncthreads();
            if ((t & 63) == 0) smem[1024 + (t >> 6)] = acc;
            __syncthreads();
            if (t < 2) {
                float sc = smem[1024 + t * 4] + smem[1024 + t * 4 + 1]
                         + smem[1024 + t * 4 + 2] + smem[1024 + t * 4 + 3];
                gstore(e + x * 64 + y * 2 + t, __expf(sc));
            }
        }
        gsync(bar, ep++);

        // ---- Phase D: h_att (blocks 0..63, 16 columns each) ----
        if (b < 64) {
            float* le = smem;          // [512]
            float* sred = smem + 512;  // [8]
            float* pr = smem + 520;    // [32][16]
            float ev = gload(e + t);
            le[t] = ev;
            float sv = wave_red(ev);
            if ((t & 63) == 0) sred[t >> 6] = sv;
            __syncthreads();
            const int kt = t & 15, rq = t >> 4;
            const int k0 = x * 128 + y * 16;
            float pp = 0.f;
#pragma unroll 4
            for (int i2 = 0; i2 < 16; i2++) {
                int r = rq * 16 + i2;
                pp = fmaf(le[r], H[(size_t)r * 1024 + k0 + kt], pp);
            }
            pr[t] = pp;
            __syncthreads();
            if (t < 16) {
                float p = 0.f;
#pragma unroll
                for (int q = 0; q < 32; q++) p += pr[q * 16 + t];
                float S = sred[0] + sred[1] + sred[2] + sred[3]
                        + sred[4] + sred[5] + sred[6] + sred[7];
                int k = k0 + t;
                float hv = Hcol[k] + gload(h_new + k) - p / S;
                gstore(h + k, hv);
                out[(size_t)st * 1024 + k] = hv;
            }
        }
        gsync(bar, ep++);
    }
}

extern "C" void kernel_launch(void* const* d_in, const int* in_sizes, int n_in,
                              void* d_out, int out_size, void* d_ws, size_t ws_size,
                              hipStream_t stream) {
    const float* inputs  = (const float*)d_in[0];   // [256,1,1024]
    const float* hiddn   = (const float*)d_in[1];   // [512,1024]
    const float* W_ioux  = (const float*)d_in[2];   // [1024,3072]
    const float* b_ioux  = (const float*)d_in[3];
    const float* W_iouh  = (const float*)d_in[4];   // [1024,3072]
    const float* b_iouh  = (const float*)d_in[5];
    const float* W_fx    = (const float*)d_in[6];   // [1024,1024]
    const float* b_fx    = (const float*)d_in[7];
    const float* W_fh    = (const float*)d_in[8];   // [1024,1024]
    const float* b_fh    = (const float*)d_in[9];
    const float* Wa      = (const float*)d_in[10];  // [1,1024]
    const float* W_attnh = (const float*)d_in[11];  // [2048,1024]
    const float* b_attnh = (const float*)d_in[12];

    float* ws = (float*)d_ws;
    float* Wg    = ws + OFF_WG;
    float* WatT  = ws + OFF_WATT;
    float* Hpre  = ws + OFF_HPRE;
    float* X_iou = ws + OFF_XIOU;
    float* X_f   = ws + OFF_XF;
    float* Hcol  = ws + OFF_HCOL;
    float* h     = ws + OFF_H;
    float* c     = ws + OFF_C;
    unsigned* bar = (unsigned*)(ws + OFF_BAR);
    float* h_new = ws + OFF_HNEW;
    float* att_v = ws + OFF_ATTV;
    float* e     = ws + OFF_E;
    float* out   = (float*)d_out;   // reference output dtype is float32

    // zero h, c, barrier slots (ws is poisoned before every timed launch)
    hipMemsetAsync(ws + OFF_H, 0, 6144 * sizeof(float), stream);

    build_wg<<<dim3(4, 1024), 256, 0, stream>>>(W_iouh, W_fh, Wg);
    transpose_k<<<dim3(32, 32), dim3(32, 8), 0, stream>>>(W_attnh, WatT);
    gemm_bias<<<dim3(48, 4), 256, 0, stream>>>(inputs, W_ioux, b_ioux, b_iouh, X_iou, 256, 3072, 1024);
    gemm_bias<<<dim3(16, 4), 256, 0, stream>>>(inputs, W_fx, b_fx, b_fh, X_f, 256, 1024, 1024);
    gemm_bias<<<dim3(16, 8), 256, 0, stream>>>(hiddn, W_attnh + 1024 * 1024, b_attnh, nullptr, Hpre, 512, 1024, 1024);
    colsum_k<<<4, 256, 0, stream>>>(hiddn, Hcol);

    recurrent<<<NBLK, NTHR, 0, stream>>>(Wg, WatT, Hpre, hiddn, Hcol, X_iou, X_f, Wa,
                                         h, c, h_new, att_v, e, bar, out);
}

// Round 6
// 4600.168 us; speedup vs baseline: 1.4076x; 1.4076x over previous
//
#include <hip/hip_runtime.h>
#include <hip/hip_bf16.h>

// ---------------- sizes ----------------
#define T_STEPS 256
#define MDIM 1024
#define MROWS 512
#define NBLK 256
#define NTHR 512

// ws float offsets
#define OFF_WGB     0u                      // bf16 [1024][4096] interleaved gates (2M floats)
#define OFF_WATT    2097152u                // fp32 [1024][1024] W_attnh top, transposed
#define OFF_HPRE    3145728u                // fp32 [512][1024]
#define OFF_XIOU    3670016u                // fp32 [256][3072]
#define OFF_XF      4456448u                // fp32 [256][1024]
#define OFF_G       4718592u                // bf16 [512][4096]  G = H @ Wg (1M floats)
#define OFF_HT      5767168u                // fp32 [1024][512]  H transposed
#define OFF_HCOL    6291456u                // fp32 [1024]
#define OFF_HCOLW   6292480u                // fp32 [4096]  Hcol @ Wg
#define OFF_HNEW    6296576u                // fp32 [1024]   (zeroed)
#define OFF_E       6297600u                // fp32 [512]    (zeroed)
#define OFF_BAR     6298112u                // 4112 u32      (zeroed)
#define OFF_ATTV    6302224u                // fp32 [1024]
// total ~6303248 floats = 25.2 MB (< proven 27.3 MB)

__device__ inline float fast_tanh(float v) {
    float x = fminf(fmaxf(v, -15.f), 15.f);
    float z = __expf(2.f * x);
    return (z - 1.f) / (z + 1.f);
}
__device__ inline float sigm(float v) { return 1.f / (1.f + __expf(-v)); }

__device__ inline float wave_red(float v) {
#pragma unroll
    for (int s = 32; s > 0; s >>= 1) v += __shfl_down(v, s, 64);
    return v;
}

__device__ __host__ inline unsigned short f2b(float f) {
    __hip_bfloat16 h = __float2bfloat16(f);
    return *(unsigned short*)&h;
}
__device__ inline float b2f(unsigned short u) {
    union { unsigned i; float f; } v; v.i = ((unsigned)u) << 16; return v.f;
}

// device-scope relaxed atomics: LLC-direct, no L2 invalidate anywhere
__device__ inline float gload(const float* p) {
    return __hip_atomic_load(p, __ATOMIC_RELAXED, __HIP_MEMORY_SCOPE_AGENT);
}
__device__ inline void gstore(float* p, float v) {
    __hip_atomic_store(p, v, __ATOMIC_RELAXED, __HIP_MEMORY_SCOPE_AGENT);
}

// Root-poller barrier: blocks release epoch to own 64B slot; ONLY block 0
// polls the 256 slots (threads 0..255, one line each), then release-stores a
// single broadcast flag; all other blocks poll that one line (thread 0 only).
// ~3 LLC hops, polling traffic confined to block 0 + one broadcast line.
__device__ inline void gsync(unsigned* bar, unsigned ep) {
    __syncthreads();
    if (threadIdx.x == 0)
        __hip_atomic_store(&bar[(blockIdx.x + 1) * 16], ep, __ATOMIC_RELEASE,
                           __HIP_MEMORY_SCOPE_AGENT);
    if (blockIdx.x == 0) {
        if (threadIdx.x < NBLK) {
            while (__hip_atomic_load(&bar[(threadIdx.x + 1) * 16], __ATOMIC_RELAXED,
                                     __HIP_MEMORY_SCOPE_AGENT) < ep)
                __builtin_amdgcn_s_sleep(1);
        }
        __syncthreads();
        if (threadIdx.x == 0)
            __hip_atomic_store(&bar[0], ep, __ATOMIC_RELEASE,
                               __HIP_MEMORY_SCOPE_AGENT);
    } else {
        if (threadIdx.x == 0) {
            while (__hip_atomic_load(&bar[0], __ATOMIC_RELAXED,
                                     __HIP_MEMORY_SCOPE_AGENT) < ep)
                __builtin_amdgcn_s_sleep(1);
        }
    }
    __asm__ volatile("" ::: "memory");
    __syncthreads();
}

// -------- precompute kernels --------

// Wgb[k][4g+{0,1,2,3}] = bf16{W_iouh[k][g], W_iouh[k][m+g], W_iouh[k][2m+g], W_fh[k][g]}
__global__ void build_wg(const float* __restrict__ Wiouh, const float* __restrict__ Wfh,
                         unsigned short* __restrict__ Wgb) {
    int k = blockIdx.y;
    int g = blockIdx.x * 256 + threadIdx.x;
    unsigned a = f2b(Wiouh[k * 3072 + g]);
    unsigned b = f2b(Wiouh[k * 3072 + 1024 + g]);
    unsigned c = f2b(Wiouh[k * 3072 + 2048 + g]);
    unsigned d = f2b(Wfh[k * 1024 + g]);
    uint2 p; p.x = a | (b << 16); p.y = c | (d << 16);
    *(uint2*)(Wgb + (size_t)k * 4096 + 4 * g) = p;
}

// dst[c*R + r] = src[r*C + c]
__global__ void transpose_g(const float* __restrict__ src, float* __restrict__ dst,
                            int R, int C) {
    __shared__ float tile[32][33];
    int c = blockIdx.x * 32 + threadIdx.x;
    int r0 = blockIdx.y * 32;
    for (int i = threadIdx.y; i < 32; i += 8)
        tile[i][threadIdx.x] = src[(size_t)(r0 + i) * C + c];
    __syncthreads();
    int r = r0 + threadIdx.x;
    int c0 = blockIdx.x * 32;
    for (int i = threadIdx.y; i < 32; i += 8)
        dst[(size_t)(c0 + i) * R + r] = tile[threadIdx.x][i];
}

// C[M,N] = A[M,K] @ B[K,N] + b1 + b2
__global__ __launch_bounds__(256) void gemm_bias(const float* __restrict__ A,
                                                 const float* __restrict__ B,
                                                 const float* __restrict__ b1,
                                                 const float* __restrict__ b2,
                                                 float* __restrict__ C,
                                                 int M, int N, int K) {
    __shared__ float As[16][68];
    __shared__ float Bs[16][68];
    int t = threadIdx.x;
    int m0 = blockIdx.y * 64, n0 = blockIdx.x * 64;
    int tx = t & 15, ty = t >> 4;
    float acc[4][4] = {};
    for (int kk = 0; kk < K; kk += 16) {
        {
            int m = t >> 2, k4 = (t & 3) * 4;
            const float4 a4 = *(const float4*)(A + (size_t)(m0 + m) * K + kk + k4);
            As[k4 + 0][m] = a4.x; As[k4 + 1][m] = a4.y;
            As[k4 + 2][m] = a4.z; As[k4 + 3][m] = a4.w;
            int kb = t >> 4, n = (t & 15) * 4;
            const float4 b4 = *(const float4*)(B + (size_t)(kk + kb) * N + n0 + n);
            *(float4*)&Bs[kb][n] = b4;
        }
        __syncthreads();
#pragma unroll
        for (int k = 0; k < 16; k++) {
            float a[4], b[4];
            *(float4*)a = *(const float4*)&As[k][ty * 4];
            *(float4*)b = *(const float4*)&Bs[k][tx * 4];
#pragma unroll
            for (int i = 0; i < 4; i++)
#pragma unroll
                for (int j = 0; j < 4; j++)
                    acc[i][j] = fmaf(a[i], b[j], acc[i][j]);
        }
        __syncthreads();
    }
#pragma unroll
    for (int i = 0; i < 4; i++) {
        int m = m0 + ty * 4 + i;
#pragma unroll
        for (int j = 0; j < 4; j++) {
            int n = n0 + tx * 4 + j;
            float v = acc[i][j];
            if (b1) v += b1[n];
            if (b2) v += b2[n];
            C[(size_t)m * N + n] = v;
        }
    }
}

// G-gemm: Gb[m][4*(n%1024) + n/1024 + cofs] = bf16( (A@B)[m][n] )
__global__ __launch_bounds__(256) void gemm_gi(const float* __restrict__ A,
                                               const float* __restrict__ B,
                                               unsigned short* __restrict__ Gb,
                                               int M, int N, int K, int cofs) {
    __shared__ float As[16][68];
    __shared__ float Bs[16][68];
    int t = threadIdx.x;
    int m0 = blockIdx.y * 64, n0 = blockIdx.x * 64;
    int tx = t & 15, ty = t >> 4;
    float acc[4][4] = {};
    for (int kk = 0; kk < K; kk += 16) {
        {
            int m = t >> 2, k4 = (t & 3) * 4;
            const float4 a4 = *(const float4*)(A + (size_t)(m0 + m) * K + kk + k4);
            As[k4 + 0][m] = a4.x; As[k4 + 1][m] = a4.y;
            As[k4 + 2][m] = a4.z; As[k4 + 3][m] = a4.w;
            int kb = t >> 4, n = (t & 15) * 4;
            const float4 b4 = *(const float4*)(B + (size_t)(kk + kb) * N + n0 + n);
            *(float4*)&Bs[kb][n] = b4;
        }
        __syncthreads();
#pragma unroll
        for (int k = 0; k < 16; k++) {
            float a[4], b[4];
            *(float4*)a = *(const float4*)&As[k][ty * 4];
            *(float4*)b = *(const float4*)&Bs[k][tx * 4];
#pragma unroll
            for (int i = 0; i < 4; i++)
#pragma unroll
                for (int j = 0; j < 4; j++)
                    acc[i][j] = fmaf(a[i], b[j], acc[i][j]);
        }
        __syncthreads();
    }
#pragma unroll
    for (int i = 0; i < 4; i++) {
        int m = m0 + ty * 4 + i;
#pragma unroll
        for (int j = 0; j < 4; j++) {
            int n = n0 + tx * 4 + j;
            int cp = 4 * (n & 1023) + (n >> 10) + cofs;
            Gb[(size_t)m * 4096 + cp] = f2b(acc[i][j]);
        }
    }
}

__global__ void colsum_k(const float* __restrict__ H, float* __restrict__ out) {
    int k = blockIdx.x * 256 + threadIdx.x;
    float s = 0.f;
#pragma unroll 8
    for (int r = 0; r < MROWS; r++) s += H[(size_t)r * MDIM + k];
    out[k] = s;
}

// HcolW[j] = sum_k Hcol[k] * Wgb[k][j]
__global__ void hcolw_k(const float* __restrict__ Hcol,
                        const unsigned short* __restrict__ Wgb,
                        float* __restrict__ HcolW) {
    int j = blockIdx.x * 256 + threadIdx.x;
    float acc = 0.f;
#pragma unroll 8
    for (int k = 0; k < 1024; k++)
        acc = fmaf(Hcol[k], b2f(Wgb[(size_t)k * 4096 + j]), acc);
    HcolW[j] = acc;
}

// -------- persistent recurrent kernel --------
__global__ __launch_bounds__(NTHR) void recurrent(
    const unsigned short* __restrict__ Wgb, const float* __restrict__ WatT,
    const float* __restrict__ Hpre, const float* __restrict__ HT,
    const float* __restrict__ Hcol, const float* __restrict__ HcolW,
    const unsigned short* __restrict__ Gb, const float* __restrict__ X_iou,
    const float* __restrict__ X_f, const float* __restrict__ Wa,
    float* h_new, float* att_v, float* e, unsigned* bar, float* out) {

    const int b = blockIdx.x, t = threadIdx.x;
    const int x = b & 7, y = b >> 3;          // XCD-contiguous slices
    const int g_col = x * 128 + y * 4;        // block's 4 output columns
    const int j0 = x * 512 + y * 16;          // block's 16 interleaved gate cols
    unsigned ep = 0;
    float creg = 0.f;                          // cell state (threads t<4)
    __shared__ float smem[2624];
    float* hs   = smem;          // 1056 padded h_new(st-1)
    float* le   = smem + 1056;   // 512 e(st-1)
    float* red  = smem + 1568;   // [32][16] h_new-dot partials
    float* red2 = smem + 2080;   // [32][16] G-corr partials
    float* sred = smem + 2592;   // 8  (S partials)
    float* sred2= smem + 2600;   // 8  (P partials)
    float* dotb = smem + 2608;   // 16

    for (int st = 0; st < T_STEPS; st++) {
        // ---- Phase A: gates + h_new + out[st-1] ----
        {
            float evv = gload(e + t);
            le[t] = evv;
            float hv0 = gload(h_new + t), hv1 = gload(h_new + t + 512);
            hs[t + (t >> 5)] = hv0;
            { int k2 = t + 512; hs[k2 + (k2 >> 5)] = hv1; }
            float sv = wave_red(evv);
            if ((t & 63) == 0) sred[t >> 6] = sv;
            __syncthreads();

            const int jt = t & 15, kq = t >> 4;
            // h_new-dot over k
            const unsigned short* wp = Wgb + (size_t)(kq * 32) * 4096 + j0 + jt;
            float acc = 0.f;
#pragma unroll 8
            for (int i = 0; i < 32; i++) {
                int k = kq * 32 + i;
                acc = fmaf(hs[k + (k >> 5)], b2f(wp[(size_t)i * 4096]), acc);
            }
            red[kq * 16 + jt] = acc;
            // G-correction over r
            const unsigned short* gp = Gb + (size_t)(kq * 16) * 4096 + j0 + jt;
            float acc2 = 0.f;
#pragma unroll 8
            for (int i = 0; i < 16; i++)
                acc2 = fmaf(le[kq * 16 + i], b2f(gp[(size_t)i * 4096]), acc2);
            red2[kq * 16 + jt] = acc2;
            // P for block's 4 out-cols: kt = t>>7, rr = t&127
            {
                const int kt = t >> 7, rr = t & 127;
                const float* htp = HT + (size_t)(g_col + kt) * 512;
                float pp = 0.f;
#pragma unroll
                for (int i = 0; i < 4; i++) {
                    int r = rr + 128 * i;
                    pp = fmaf(le[r], htp[r], pp);
                }
                pp = wave_red(pp);
                if ((t & 63) == 0) sred2[t >> 6] = pp;
            }
            __syncthreads();
            if (t < 16) {
                float s1 = 0.f, s2 = 0.f;
#pragma unroll
                for (int q = 0; q < 32; q++) { s1 += red[q * 16 + t]; s2 += red2[q * 16 + t]; }
                float S = sred[0] + sred[1] + sred[2] + sred[3]
                        + sred[4] + sred[5] + sred[6] + sred[7];
                float invS = (st == 0) ? 0.f : 1.f / S;
                float hw = (st == 0) ? 0.f : HcolW[j0 + t];
                dotb[t] = s1 + hw - invS * s2;
            }
            __syncthreads();
            if (t < 4) {
                int g = g_col + t;
                float S = sred[0] + sred[1] + sred[2] + sred[3]
                        + sred[4] + sred[5] + sred[6] + sred[7];
                if (st > 0) {
                    float P = sred2[t * 2] + sred2[t * 2 + 1];
                    out[(size_t)(st - 1) * 1024 + g] =
                        Hcol[g] + hs[g + (g >> 5)] - P / S;
                }
                float di = dotb[t * 4 + 0] + X_iou[(size_t)st * 3072 + g];
                float doo = dotb[t * 4 + 1] + X_iou[(size_t)st * 3072 + 1024 + g];
                float du = dotb[t * 4 + 2] + X_iou[(size_t)st * 3072 + 2048 + g];
                float df = dotb[t * 4 + 3] + X_f[(size_t)st * 1024 + g];
                float ig = sigm(di), og = sigm(doo), fg = sigm(df);
                float ug = fast_tanh(du);
                creg = ig * ug + fg * creg;
                gstore(h_new + g, og * fast_tanh(creg));
            }
        }
        gsync(bar, ++ep);

        // ---- Phase B: att_v = h_new @ W_attnh_top (4 rows per block) ----
        {
            float* hn = smem;
            hn[t] = gload(h_new + t);
            hn[t + 512] = gload(h_new + t + 512);
            __syncthreads();
            const int tr = t >> 7, li = t & 127;
            int j = x * 128 + y * 4 + tr;
            const float* wr = WatT + (size_t)j * 1024;
            float4 w0 = *(const float4*)(wr + li * 4);
            float4 w1 = *(const float4*)(wr + 512 + li * 4);
            float4 a0 = *(const float4*)&hn[li * 4];
            float4 a1 = *(const float4*)&hn[512 + li * 4];
            float acc = w0.x * a0.x + w0.y * a0.y + w0.z * a0.z + w0.w * a0.w
                      + w1.x * a1.x + w1.y * a1.y + w1.z * a1.z + w1.w * a1.w;
            acc = wave_red(acc);
            __syncthreads();
            if ((t & 63) == 0) smem[1024 + (t >> 6)] = acc;
            __syncthreads();
            if (t < 4) gstore(att_v + x * 128 + y * 4 + t,
                              smem[1024 + t * 2] + smem[1024 + t * 2 + 1]);
        }
        gsync(bar, ++ep);

        // ---- Phase C: scores -> e (2 rows per block) ----
        {
            float* av = smem;
            av[t] = gload(att_v + t);
            av[t + 512] = gload(att_v + t + 512);
            __syncthreads();
            const int rr = t >> 8, li = t & 255;
            int r = x * 64 + y * 2 + rr;
            int k4 = li * 4;
            float4 hp = *(const float4*)(Hpre + (size_t)r * 1024 + k4);
            float4 a4 = *(const float4*)&av[k4];
            float4 wa = *(const float4*)(Wa + k4);
            float acc = fast_tanh(hp.x + a4.x) * wa.x + fast_tanh(hp.y + a4.y) * wa.y
                      + fast_tanh(hp.z + a4.z) * wa.z + fast_tanh(hp.w + a4.w) * wa.w;
            acc = wave_red(acc);
            __syncthreads();
            if ((t & 63) == 0) smem[1024 + (t >> 6)] = acc;
            __syncthreads();
            if (t < 2) {
                float sc = smem[1024 + t * 4] + smem[1024 + t * 4 + 1]
                         + smem[1024 + t * 4 + 2] + smem[1024 + t * 4 + 3];
                gstore(e + x * 64 + y * 2 + t, __expf(sc));
            }
        }
        gsync(bar, ++ep);
    }

    // ---- Epilogue: out[T-1] ----
    {
        float evv = gload(e + t);
        le[t] = evv;
        float sv = wave_red(evv);
        if ((t & 63) == 0) sred[t >> 6] = sv;
        __syncthreads();
        const int kt = t >> 7, rr = t & 127;
        const float* htp = HT + (size_t)(g_col + kt) * 512;
        float pp = 0.f;
#pragma unroll
        for (int i = 0; i < 4; i++) {
            int r = rr + 128 * i;
            pp = fmaf(le[r], htp[r], pp);
        }
        pp = wave_red(pp);
        if ((t & 63) == 0) sred2[t >> 6] = pp;
        __syncthreads();
        if (t < 4) {
            int g = g_col + t;
            float S = sred[0] + sred[1] + sred[2] + sred[3]
                    + sred[4] + sred[5] + sred[6] + sred[7];
            float P = sred2[t * 2] + sred2[t * 2 + 1];
            out[(size_t)(T_STEPS - 1) * 1024 + g] =
                Hcol[g] + gload(h_new + g) - P / S;
        }
    }
}

extern "C" void kernel_launch(void* const* d_in, const int* in_sizes, int n_in,
                              void* d_out, int out_size, void* d_ws, size_t ws_size,
                              hipStream_t stream) {
    const float* inputs  = (const float*)d_in[0];
    const float* hiddn   = (const float*)d_in[1];
    const float* W_ioux  = (const float*)d_in[2];
    const float* b_ioux  = (const float*)d_in[3];
    const float* W_iouh  = (const float*)d_in[4];
    const float* b_iouh  = (const float*)d_in[5];
    const float* W_fx    = (const float*)d_in[6];
    const float* b_fx    = (const float*)d_in[7];
    const float* W_fh    = (const float*)d_in[8];
    const float* b_fh    = (const float*)d_in[9];
    const float* Wa      = (const float*)d_in[10];
    const float* W_attnh = (const float*)d_in[11];
    const float* b_attnh = (const float*)d_in[12];

    float* ws = (float*)d_ws;
    unsigned short* Wgb = (unsigned short*)(ws + OFF_WGB);
    float* WatT  = ws + OFF_WATT;
    float* Hpre  = ws + OFF_HPRE;
    float* X_iou = ws + OFF_XIOU;
    float* X_f   = ws + OFF_XF;
    unsigned short* Gb = (unsigned short*)(ws + OFF_G);
    float* HT    = ws + OFF_HT;
    float* Hcol  = ws + OFF_HCOL;
    float* HcolW = ws + OFF_HCOLW;
    float* h_new = ws + OFF_HNEW;
    float* e     = ws + OFF_E;
    unsigned* bar = (unsigned*)(ws + OFF_BAR);
    float* att_v = ws + OFF_ATTV;
    float* out   = (float*)d_out;

    // zero h_new, e, barrier (contiguous region)
    hipMemsetAsync(ws + OFF_HNEW, 0, (1024 + 512 + 4112) * sizeof(float), stream);

    build_wg<<<dim3(4, 1024), 256, 0, stream>>>(W_iouh, W_fh, Wgb);
    transpose_g<<<dim3(32, 32), dim3(32, 8), 0, stream>>>(W_attnh, WatT, 1024, 1024);
    transpose_g<<<dim3(32, 16), dim3(32, 8), 0, stream>>>(hiddn, HT, 512, 1024);
    gemm_bias<<<dim3(48, 4), 256, 0, stream>>>(inputs, W_ioux, b_ioux, b_iouh, X_iou, 256, 3072, 1024);
    gemm_bias<<<dim3(16, 4), 256, 0, stream>>>(inputs, W_fx, b_fx, b_fh, X_f, 256, 1024, 1024);
    gemm_bias<<<dim3(16, 8), 256, 0, stream>>>(hiddn, W_attnh + 1024 * 1024, b_attnh, nullptr, Hpre, 512, 1024, 1024);
    colsum_k<<<4, 256, 0, stream>>>(hiddn, Hcol);
    hcolw_k<<<16, 256, 0, stream>>>(Hcol, Wgb, HcolW);
    gemm_gi<<<dim3(48, 8), 256, 0, stream>>>(hiddn, W_iouh, Gb, 512, 3072, 1024, 0);
    gemm_gi<<<dim3(16, 8), 256, 0, stream>>>(hiddn, W_fh, Gb, 512, 1024, 1024, 3);

    recurrent<<<NBLK, NTHR, 0, stream>>>(Wgb, WatT, Hpre, HT, Hcol, HcolW, Gb,
                                         X_iou, X_f, Wa, h_new, att_v, e, bar, out);
}

// Round 7
// 3478.979 us; speedup vs baseline: 1.8612x; 1.3223x over previous
//
#include <hip/hip_runtime.h>
#include <hip/hip_bf16.h>

// ---------------- sizes ----------------
#define T_STEPS 256
#define MDIM 1024
#define MROWS 512
#define NBLK 256
#define NTHR 512

// ws float offsets
#define OFF_WGB     0u                      // bf16 [1024][4096] interleaved gates (2M floats)
#define OFF_WATT    2097152u                // fp32 [1024][1024] W_attnh top, transposed
#define OFF_HPRE    3145728u                // fp32 [512][1024]
#define OFF_XIOU    3670016u                // fp32 [256][3072]
#define OFF_XF      4456448u                // fp32 [256][1024]
#define OFF_G       4718592u                // bf16 [512][4096]  G = H @ Wg (1M floats)
#define OFF_HT      5767168u                // fp32 [1024][512]  H transposed
#define OFF_HCOL    6291456u                // fp32 [1024]
#define OFF_HCOLW   6292480u                // fp32 [4096]  Hcol @ Wg
#define OFF_HNEW    6296576u                // fp32 [1024]   (zeroed)
#define OFF_E       6297600u                // fp32 [512]    (zeroed)
#define OFF_BAR     6298112u                // 4112 u32      (zeroed)
#define OFF_ATTV    6302224u                // fp32 [1024]

__device__ inline float fast_tanh(float v) {
    float x = fminf(fmaxf(v, -15.f), 15.f);
    float z = __expf(2.f * x);
    return (z - 1.f) / (z + 1.f);
}
__device__ inline float sigm(float v) { return 1.f / (1.f + __expf(-v)); }

__device__ inline float wave_red(float v) {
#pragma unroll
    for (int s = 32; s > 0; s >>= 1) v += __shfl_down(v, s, 64);
    return v;
}

__device__ __host__ inline unsigned short f2b(float f) {
    __hip_bfloat16 h = __float2bfloat16(f);
    return *(unsigned short*)&h;
}
__device__ inline float b2f(unsigned short u) {
    union { unsigned i; float f; } v; v.i = ((unsigned)u) << 16; return v.f;
}

// device-scope relaxed atomics: LLC-direct, no L2 invalidate anywhere
__device__ inline float gload(const float* p) {
    return __hip_atomic_load(p, __ATOMIC_RELAXED, __HIP_MEMORY_SCOPE_AGENT);
}
__device__ inline void gstore(float* p, float v) {
    __hip_atomic_store(p, v, __ATOMIC_RELAXED, __HIP_MEMORY_SCOPE_AGENT);
}

// Root-poller barrier, ALL-RELAXED (round-7 change: no release anywhere).
// Rationale: agent-scope RELEASE forces a conservative dirty-L2 writeback
// (~µs, topology-invariant constant we measured across 3 barrier shapes).
// Data stores are agent-scope relaxed atomics that complete AT THE LLC, and
// __syncthreads drains vmcnt before s_barrier — so when thread 0 issues the
// slot store, the block's data is already LLC-visible. s_waitcnt(0) is
// belt-and-braces. Flag/slot stores can therefore be RELAXED.
__device__ inline void gsync(unsigned* bar, unsigned ep) {
    __syncthreads();
    __builtin_amdgcn_s_waitcnt(0);
    if (threadIdx.x == 0)
        __hip_atomic_store(&bar[(blockIdx.x + 1) * 16], ep, __ATOMIC_RELAXED,
                           __HIP_MEMORY_SCOPE_AGENT);
    if (blockIdx.x == 0) {
        if (threadIdx.x < NBLK) {
            while (__hip_atomic_load(&bar[(threadIdx.x + 1) * 16], __ATOMIC_RELAXED,
                                     __HIP_MEMORY_SCOPE_AGENT) < ep)
                __builtin_amdgcn_s_sleep(1);
        }
        __syncthreads();
        if (threadIdx.x == 0)
            __hip_atomic_store(&bar[0], ep, __ATOMIC_RELAXED,
                               __HIP_MEMORY_SCOPE_AGENT);
    } else {
        if (threadIdx.x == 0) {
            while (__hip_atomic_load(&bar[0], __ATOMIC_RELAXED,
                                     __HIP_MEMORY_SCOPE_AGENT) < ep)
                __builtin_amdgcn_s_sleep(1);
        }
    }
    __asm__ volatile("" ::: "memory");
    __syncthreads();
}

// -------- precompute kernels --------

// Wgb[k][4g+{0,1,2,3}] = bf16{W_iouh[k][g], W_iouh[k][m+g], W_iouh[k][2m+g], W_fh[k][g]}
__global__ void build_wg(const float* __restrict__ Wiouh, const float* __restrict__ Wfh,
                         unsigned short* __restrict__ Wgb) {
    int k = blockIdx.y;
    int g = blockIdx.x * 256 + threadIdx.x;
    unsigned a = f2b(Wiouh[k * 3072 + g]);
    unsigned b = f2b(Wiouh[k * 3072 + 1024 + g]);
    unsigned c = f2b(Wiouh[k * 3072 + 2048 + g]);
    unsigned d = f2b(Wfh[k * 1024 + g]);
    uint2 p; p.x = a | (b << 16); p.y = c | (d << 16);
    *(uint2*)(Wgb + (size_t)k * 4096 + 4 * g) = p;
}

// dst[c*R + r] = src[r*C + c]
__global__ void transpose_g(const float* __restrict__ src, float* __restrict__ dst,
                            int R, int C) {
    __shared__ float tile[32][33];
    int c = blockIdx.x * 32 + threadIdx.x;
    int r0 = blockIdx.y * 32;
    for (int i = threadIdx.y; i < 32; i += 8)
        tile[i][threadIdx.x] = src[(size_t)(r0 + i) * C + c];
    __syncthreads();
    int r = r0 + threadIdx.x;
    int c0 = blockIdx.x * 32;
    for (int i = threadIdx.y; i < 32; i += 8)
        dst[(size_t)(c0 + i) * R + r] = tile[threadIdx.x][i];
}

// C[M,N] = A[M,K] @ B[K,N] + b1 + b2
__global__ __launch_bounds__(256) void gemm_bias(const float* __restrict__ A,
                                                 const float* __restrict__ B,
                                                 const float* __restrict__ b1,
                                                 const float* __restrict__ b2,
                                                 float* __restrict__ C,
                                                 int M, int N, int K) {
    __shared__ float As[16][68];
    __shared__ float Bs[16][68];
    int t = threadIdx.x;
    int m0 = blockIdx.y * 64, n0 = blockIdx.x * 64;
    int tx = t & 15, ty = t >> 4;
    float acc[4][4] = {};
    for (int kk = 0; kk < K; kk += 16) {
        {
            int m = t >> 2, k4 = (t & 3) * 4;
            const float4 a4 = *(const float4*)(A + (size_t)(m0 + m) * K + kk + k4);
            As[k4 + 0][m] = a4.x; As[k4 + 1][m] = a4.y;
            As[k4 + 2][m] = a4.z; As[k4 + 3][m] = a4.w;
            int kb = t >> 4, n = (t & 15) * 4;
            const float4 b4 = *(const float4*)(B + (size_t)(kk + kb) * N + n0 + n);
            *(float4*)&Bs[kb][n] = b4;
        }
        __syncthreads();
#pragma unroll
        for (int k = 0; k < 16; k++) {
            float a[4], b[4];
            *(float4*)a = *(const float4*)&As[k][ty * 4];
            *(float4*)b = *(const float4*)&Bs[k][tx * 4];
#pragma unroll
            for (int i = 0; i < 4; i++)
#pragma unroll
                for (int j = 0; j < 4; j++)
                    acc[i][j] = fmaf(a[i], b[j], acc[i][j]);
        }
        __syncthreads();
    }
#pragma unroll
    for (int i = 0; i < 4; i++) {
        int m = m0 + ty * 4 + i;
#pragma unroll
        for (int j = 0; j < 4; j++) {
            int n = n0 + tx * 4 + j;
            float v = acc[i][j];
            if (b1) v += b1[n];
            if (b2) v += b2[n];
            C[(size_t)m * N + n] = v;
        }
    }
}

// G-gemm: Gb[m][4*(n%1024) + n/1024 + cofs] = bf16( (A@B)[m][n] )
__global__ __launch_bounds__(256) void gemm_gi(const float* __restrict__ A,
                                               const float* __restrict__ B,
                                               unsigned short* __restrict__ Gb,
                                               int M, int N, int K, int cofs) {
    __shared__ float As[16][68];
    __shared__ float Bs[16][68];
    int t = threadIdx.x;
    int m0 = blockIdx.y * 64, n0 = blockIdx.x * 64;
    int tx = t & 15, ty = t >> 4;
    float acc[4][4] = {};
    for (int kk = 0; kk < K; kk += 16) {
        {
            int m = t >> 2, k4 = (t & 3) * 4;
            const float4 a4 = *(const float4*)(A + (size_t)(m0 + m) * K + kk + k4);
            As[k4 + 0][m] = a4.x; As[k4 + 1][m] = a4.y;
            As[k4 + 2][m] = a4.z; As[k4 + 3][m] = a4.w;
            int kb = t >> 4, n = (t & 15) * 4;
            const float4 b4 = *(const float4*)(B + (size_t)(kk + kb) * N + n0 + n);
            *(float4*)&Bs[kb][n] = b4;
        }
        __syncthreads();
#pragma unroll
        for (int k = 0; k < 16; k++) {
            float a[4], b[4];
            *(float4*)a = *(const float4*)&As[k][ty * 4];
            *(float4*)b = *(const float4*)&Bs[k][tx * 4];
#pragma unroll
            for (int i = 0; i < 4; i++)
#pragma unroll
                for (int j = 0; j < 4; j++)
                    acc[i][j] = fmaf(a[i], b[j], acc[i][j]);
        }
        __syncthreads();
    }
#pragma unroll
    for (int i = 0; i < 4; i++) {
        int m = m0 + ty * 4 + i;
#pragma unroll
        for (int j = 0; j < 4; j++) {
            int n = n0 + tx * 4 + j;
            int cp = 4 * (n & 1023) + (n >> 10) + cofs;
            Gb[(size_t)m * 4096 + cp] = f2b(acc[i][j]);
        }
    }
}

__global__ void colsum_k(const float* __restrict__ H, float* __restrict__ out) {
    int k = blockIdx.x * 256 + threadIdx.x;
    float s = 0.f;
#pragma unroll 8
    for (int r = 0; r < MROWS; r++) s += H[(size_t)r * MDIM + k];
    out[k] = s;
}

// HcolW[j] = sum_k Hcol[k] * Wgb[k][j]
__global__ void hcolw_k(const float* __restrict__ Hcol,
                        const unsigned short* __restrict__ Wgb,
                        float* __restrict__ HcolW) {
    int j = blockIdx.x * 256 + threadIdx.x;
    float acc = 0.f;
#pragma unroll 8
    for (int k = 0; k < 1024; k++)
        acc = fmaf(Hcol[k], b2f(Wgb[(size_t)k * 4096 + j]), acc);
    HcolW[j] = acc;
}

// -------- persistent recurrent kernel --------
__global__ __launch_bounds__(NTHR) void recurrent(
    const unsigned short* __restrict__ Wgb, const float* __restrict__ WatT,
    const float* __restrict__ Hpre, const float* __restrict__ HT,
    const float* __restrict__ Hcol, const float* __restrict__ HcolW,
    const unsigned short* __restrict__ Gb, const float* __restrict__ X_iou,
    const float* __restrict__ X_f, const float* __restrict__ Wa,
    float* h_new, float* att_v, float* e, unsigned* bar, float* out) {

    const int b = blockIdx.x, t = threadIdx.x;
    const int x = b & 7, y = b >> 3;          // XCD-contiguous slices
    const int g_col = x * 128 + y * 4;        // block's 4 output columns
    const int j0 = x * 512 + y * 16;          // block's 16 interleaved gate cols
    unsigned ep = 0;
    float creg = 0.f;                          // cell state (threads t<4)
    __shared__ float smem[2624];
    float* hs   = smem;          // 1056 padded h_new(st-1)
    float* le   = smem + 1056;   // 512 e(st-1)
    float* red  = smem + 1568;   // [32][16] h_new-dot partials
    float* red2 = smem + 2080;   // [32][16] G-corr partials
    float* sred = smem + 2592;   // 8  (S partials)
    float* sred2= smem + 2600;   // 8  (P partials)
    float* dotb = smem + 2608;   // 16

    for (int st = 0; st < T_STEPS; st++) {
        // ---- Phase A: gates + h_new + out[st-1] ----
        {
            float evv = gload(e + t);
            le[t] = evv;
            float hv0 = gload(h_new + t), hv1 = gload(h_new + t + 512);
            hs[t + (t >> 5)] = hv0;
            { int k2 = t + 512; hs[k2 + (k2 >> 5)] = hv1; }
            float sv = wave_red(evv);
            if ((t & 63) == 0) sred[t >> 6] = sv;
            __syncthreads();

            const int jt = t & 15, kq = t >> 4;
            // h_new-dot over k
            const unsigned short* wp = Wgb + (size_t)(kq * 32) * 4096 + j0 + jt;
            float acc = 0.f;
#pragma unroll 8
            for (int i = 0; i < 32; i++) {
                int k = kq * 32 + i;
                acc = fmaf(hs[k + (k >> 5)], b2f(wp[(size_t)i * 4096]), acc);
            }
            red[kq * 16 + jt] = acc;
            // G-correction over r
            const unsigned short* gp = Gb + (size_t)(kq * 16) * 4096 + j0 + jt;
            float acc2 = 0.f;
#pragma unroll 8
            for (int i = 0; i < 16; i++)
                acc2 = fmaf(le[kq * 16 + i], b2f(gp[(size_t)i * 4096]), acc2);
            red2[kq * 16 + jt] = acc2;
            // P for block's 4 out-cols
            {
                const int kt = t >> 7, rr = t & 127;
                const float* htp = HT + (size_t)(g_col + kt) * 512;
                float pp = 0.f;
#pragma unroll
                for (int i = 0; i < 4; i++) {
                    int r = rr + 128 * i;
                    pp = fmaf(le[r], htp[r], pp);
                }
                pp = wave_red(pp);
                if ((t & 63) == 0) sred2[t >> 6] = pp;
            }
            __syncthreads();
            if (t < 16) {
                float s1 = 0.f, s2 = 0.f;
#pragma unroll
                for (int q = 0; q < 32; q++) { s1 += red[q * 16 + t]; s2 += red2[q * 16 + t]; }
                float S = sred[0] + sred[1] + sred[2] + sred[3]
                        + sred[4] + sred[5] + sred[6] + sred[7];
                float invS = (st == 0) ? 0.f : 1.f / S;
                float hw = (st == 0) ? 0.f : HcolW[j0 + t];
                dotb[t] = s1 + hw - invS * s2;
            }
            __syncthreads();
            if (t < 4) {
                int g = g_col + t;
                float S = sred[0] + sred[1] + sred[2] + sred[3]
                        + sred[4] + sred[5] + sred[6] + sred[7];
                if (st > 0) {
                    float P = sred2[t * 2] + sred2[t * 2 + 1];
                    out[(size_t)(st - 1) * 1024 + g] =
                        Hcol[g] + hs[g + (g >> 5)] - P / S;
                }
                float di = dotb[t * 4 + 0] + X_iou[(size_t)st * 3072 + g];
                float doo = dotb[t * 4 + 1] + X_iou[(size_t)st * 3072 + 1024 + g];
                float du = dotb[t * 4 + 2] + X_iou[(size_t)st * 3072 + 2048 + g];
                float df = dotb[t * 4 + 3] + X_f[(size_t)st * 1024 + g];
                float ig = sigm(di), og = sigm(doo), fg = sigm(df);
                float ug = fast_tanh(du);
                creg = ig * ug + fg * creg;
                gstore(h_new + g, og * fast_tanh(creg));
            }
        }
        gsync(bar, ++ep);

        // ---- Phase B: att_v = h_new @ W_attnh_top (4 rows per block) ----
        {
            float* hn = smem;
            hn[t] = gload(h_new + t);
            hn[t + 512] = gload(h_new + t + 512);
            __syncthreads();
            const int tr = t >> 7, li = t & 127;
            int j = x * 128 + y * 4 + tr;
            const float* wr = WatT + (size_t)j * 1024;
            float4 w0 = *(const float4*)(wr + li * 4);
            float4 w1 = *(const float4*)(wr + 512 + li * 4);
            float4 a0 = *(const float4*)&hn[li * 4];
            float4 a1 = *(const float4*)&hn[512 + li * 4];
            float acc = w0.x * a0.x + w0.y * a0.y + w0.z * a0.z + w0.w * a0.w
                      + w1.x * a1.x + w1.y * a1.y + w1.z * a1.z + w1.w * a1.w;
            acc = wave_red(acc);
            __syncthreads();
            if ((t & 63) == 0) smem[1024 + (t >> 6)] = acc;
            __syncthreads();
            if (t < 4) gstore(att_v + x * 128 + y * 4 + t,
                              smem[1024 + t * 2] + smem[1024 + t * 2 + 1]);
        }
        gsync(bar, ++ep);

        // ---- Phase C: scores -> e (2 rows per block) ----
        {
            float* av = smem;
            av[t] = gload(att_v + t);
            av[t + 512] = gload(att_v + t + 512);
            __syncthreads();
            const int rr = t >> 8, li = t & 255;
            int r = x * 64 + y * 2 + rr;
            int k4 = li * 4;
            float4 hp = *(const float4*)(Hpre + (size_t)r * 1024 + k4);
            float4 a4 = *(const float4*)&av[k4];
            float4 wa = *(const float4*)(Wa + k4);
            float acc = fast_tanh(hp.x + a4.x) * wa.x + fast_tanh(hp.y + a4.y) * wa.y
                      + fast_tanh(hp.z + a4.z) * wa.z + fast_tanh(hp.w + a4.w) * wa.w;
            acc = wave_red(acc);
            __syncthreads();
            if ((t & 63) == 0) smem[1024 + (t >> 6)] = acc;
            __syncthreads();
            if (t < 2) {
                float sc = smem[1024 + t * 4] + smem[1024 + t * 4 + 1]
                         + smem[1024 + t * 4 + 2] + smem[1024 + t * 4 + 3];
                gstore(e + x * 64 + y * 2 + t, __expf(sc));
            }
        }
        gsync(bar, ++ep);
    }

    // ---- Epilogue: out[T-1] ----
    {
        float evv = gload(e + t);
        le[t] = evv;
        float sv = wave_red(evv);
        if ((t & 63) == 0) sred[t >> 6] = sv;
        __syncthreads();
        const int kt = t >> 7, rr = t & 127;
        const float* htp = HT + (size_t)(g_col + kt) * 512;
        float pp = 0.f;
#pragma unroll
        for (int i = 0; i < 4; i++) {
            int r = rr + 128 * i;
            pp = fmaf(le[r], htp[r], pp);
        }
        pp = wave_red(pp);
        if ((t & 63) == 0) sred2[t >> 6] = pp;
        __syncthreads();
        if (t < 4) {
            int g = g_col + t;
            float S = sred[0] + sred[1] + sred[2] + sred[3]
                    + sred[4] + sred[5] + sred[6] + sred[7];
            float P = sred2[t * 2] + sred2[t * 2 + 1];
            out[(size_t)(T_STEPS - 1) * 1024 + g] =
                Hcol[g] + gload(h_new + g) - P / S;
        }
    }
}

extern "C" void kernel_launch(void* const* d_in, const int* in_sizes, int n_in,
                              void* d_out, int out_size, void* d_ws, size_t ws_size,
                              hipStream_t stream) {
    const float* inputs  = (const float*)d_in[0];
    const float* hiddn   = (const float*)d_in[1];
    const float* W_ioux  = (const float*)d_in[2];
    const float* b_ioux  = (const float*)d_in[3];
    const float* W_iouh  = (const float*)d_in[4];
    const float* b_iouh  = (const float*)d_in[5];
    const float* W_fx    = (const float*)d_in[6];
    const float* b_fx    = (const float*)d_in[7];
    const float* W_fh    = (const float*)d_in[8];
    const float* b_fh    = (const float*)d_in[9];
    const float* Wa      = (const float*)d_in[10];
    const float* W_attnh = (const float*)d_in[11];
    const float* b_attnh = (const float*)d_in[12];

    float* ws = (float*)d_ws;
    unsigned short* Wgb = (unsigned short*)(ws + OFF_WGB);
    float* WatT  = ws + OFF_WATT;
    float* Hpre  = ws + OFF_HPRE;
    float* X_iou = ws + OFF_XIOU;
    float* X_f   = ws + OFF_XF;
    unsigned short* Gb = (unsigned short*)(ws + OFF_G);
    float* HT    = ws + OFF_HT;
    float* Hcol  = ws + OFF_HCOL;
    float* HcolW = ws + OFF_HCOLW;
    float* h_new = ws + OFF_HNEW;
    float* e     = ws + OFF_E;
    unsigned* bar = (unsigned*)(ws + OFF_BAR);
    float* att_v = ws + OFF_ATTV;
    float* out   = (float*)d_out;

    // zero h_new, e, barrier (contiguous region)
    hipMemsetAsync(ws + OFF_HNEW, 0, (1024 + 512 + 4112) * sizeof(float), stream);

    build_wg<<<dim3(4, 1024), 256, 0, stream>>>(W_iouh, W_fh, Wgb);
    transpose_g<<<dim3(32, 32), dim3(32, 8), 0, stream>>>(W_attnh, WatT, 1024, 1024);
    transpose_g<<<dim3(32, 16), dim3(32, 8), 0, stream>>>(hiddn, HT, 512, 1024);
    gemm_bias<<<dim3(48, 4), 256, 0, stream>>>(inputs, W_ioux, b_ioux, b_iouh, X_iou, 256, 3072, 1024);
    gemm_bias<<<dim3(16, 4), 256, 0, stream>>>(inputs, W_fx, b_fx, b_fh, X_f, 256, 1024, 1024);
    gemm_bias<<<dim3(16, 8), 256, 0, stream>>>(hiddn, W_attnh + 1024 * 1024, b_attnh, nullptr, Hpre, 512, 1024, 1024);
    colsum_k<<<4, 256, 0, stream>>>(hiddn, Hcol);
    hcolw_k<<<16, 256, 0, stream>>>(Hcol, Wgb, HcolW);
    gemm_gi<<<dim3(48, 8), 256, 0, stream>>>(hiddn, W_iouh, Gb, 512, 3072, 1024, 0);
    gemm_gi<<<dim3(16, 8), 256, 0, stream>>>(hiddn, W_fh, Gb, 512, 1024, 1024, 3);

    recurrent<<<NBLK, NTHR, 0, stream>>>(Wgb, WatT, Hpre, HT, Hcol, HcolW, Gb,
                                         X_iou, X_f, Wa, h_new, att_v, e, bar, out);
}